// Round 9
// baseline (2808.992 us; speedup 1.0000x reference)
//
#include <hip/hip_runtime.h>
#include <cmath>

// T=512, B=32, D=1024, H=1024, 3H=3072
// d_out: outputs (512*32*1024) ++ outputs[-1] (32*1024) ++ h_last (32*1024)  fp32

typedef short s8v  __attribute__((ext_vector_type(8)));   // 8 x bf16 (raw bits)
typedef float f4v  __attribute__((ext_vector_type(4)));   // MFMA accumulator

#define NB 64       // blocks in the GRU grid
#define GUARD 16384 // bounded-spin: degrade to wrong-answer instead of hanging

__device__ __forceinline__ short f2bf(float f) {
    return __builtin_bit_cast(short, (__bf16)f);          // RNE convert
}
__device__ __forceinline__ float bf2f(short s) {
    return (float)__builtin_bit_cast(__bf16, s);
}

// ---------------------------------------------------------------------------
// Transpose W [1024][3072] fp32  ->  Wt [3072][1024] bf16.
// ---------------------------------------------------------------------------
__global__ __launch_bounds__(256) void k_transpose_bf16(
        const float* __restrict__ W, short* __restrict__ Wt) {
    __shared__ short Ls[32][72];
    int bk = blockIdx.x & 31;
    int bn = blockIdx.x >> 5;
    int k0 = bk * 32, n0 = bn * 64;
    int tid = threadIdx.x;
    {
        int r  = tid >> 3;
        int c0 = (tid & 7) * 8;
        const float* src = W + (size_t)(k0 + r) * 3072 + n0 + c0;
        float4 f0 = *reinterpret_cast<const float4*>(src);
        float4 f1 = *reinterpret_cast<const float4*>(src + 4);
        Ls[r][c0+0] = f2bf(f0.x); Ls[r][c0+1] = f2bf(f0.y);
        Ls[r][c0+2] = f2bf(f0.z); Ls[r][c0+3] = f2bf(f0.w);
        Ls[r][c0+4] = f2bf(f1.x); Ls[r][c0+5] = f2bf(f1.y);
        Ls[r][c0+6] = f2bf(f1.z); Ls[r][c0+7] = f2bf(f1.w);
    }
    __syncthreads();
    {
        int j   = tid >> 2;
        int kk0 = (tid & 3) * 8;
        s8v v;
        #pragma unroll
        for (int s = 0; s < 8; ++s) v[s] = Ls[kk0 + s][j];
        *reinterpret_cast<s8v*>(Wt + (size_t)(n0 + j) * 1024 + k0 + kk0) = v;
    }
}

// ---------------------------------------------------------------------------
// gi = X @ W_ih.  M=16384, N=3072, K=1024.  Output bf16.
// v12: 128x128 tile, 4 waves, 4x4 16x16 frags/wave (4x MFMA per barrier vs
// the old 64x64 tile). Same fragment convention / staging dtype path / K
// order as the verified 64x64 kernel -> gi bitwise identical.
// ---------------------------------------------------------------------------
__global__ __launch_bounds__(256) void k_gemm_gi(
        const float* __restrict__ X, const short* __restrict__ Wt,
        short* __restrict__ gi) {
    __shared__ short As[128][40];
    __shared__ short Bs[128][40];
    int bm = blockIdx.x & 127;           // 128 m-blocks x 128 rows
    int bn = blockIdx.x >> 7;            // 24 n-blocks x 128 cols
    int m0 = bm * 128, n0 = bn * 128;
    int tid = threadIdx.x;
    int wid = tid >> 6, l = tid & 63;
    int wm = wid >> 1, wn = wid & 1;     // wave quadrant (64x64 each)
    int lr = l & 15, q = l >> 4;
    f4v acc[4][4] = {};
    int sr = tid >> 1;                   // 0..127 staging row
    int sc = (tid & 1) * 16;             // 0 or 16

    for (int kc = 0; kc < 1024; kc += 32) {
        const float* asrc = X + (size_t)(m0 + sr) * 1024 + kc + sc;
        float4 f0 = *reinterpret_cast<const float4*>(asrc);
        float4 f1 = *reinterpret_cast<const float4*>(asrc + 4);
        float4 f2 = *reinterpret_cast<const float4*>(asrc + 8);
        float4 f3 = *reinterpret_cast<const float4*>(asrc + 12);
        s8v av0, av1;
        av0[0]=f2bf(f0.x); av0[1]=f2bf(f0.y); av0[2]=f2bf(f0.z); av0[3]=f2bf(f0.w);
        av0[4]=f2bf(f1.x); av0[5]=f2bf(f1.y); av0[6]=f2bf(f1.z); av0[7]=f2bf(f1.w);
        av1[0]=f2bf(f2.x); av1[1]=f2bf(f2.y); av1[2]=f2bf(f2.z); av1[3]=f2bf(f2.w);
        av1[4]=f2bf(f3.x); av1[5]=f2bf(f3.y); av1[6]=f2bf(f3.z); av1[7]=f2bf(f3.w);
        *reinterpret_cast<s8v*>(&As[sr][sc])     = av0;
        *reinterpret_cast<s8v*>(&As[sr][sc + 8]) = av1;
        const short* bsrc = Wt + (size_t)(n0 + sr) * 1024 + kc + sc;
        *reinterpret_cast<s8v*>(&Bs[sr][sc])     = *reinterpret_cast<const s8v*>(bsrc);
        *reinterpret_cast<s8v*>(&Bs[sr][sc + 8]) = *reinterpret_cast<const s8v*>(bsrc + 8);
        __syncthreads();
        s8v af[4], bf[4];
        #pragma unroll
        for (int ms = 0; ms < 4; ++ms)
            af[ms] = *reinterpret_cast<const s8v*>(&As[wm*64 + ms*16 + lr][q*8]);
        #pragma unroll
        for (int ns = 0; ns < 4; ++ns)
            bf[ns] = *reinterpret_cast<const s8v*>(&Bs[wn*64 + ns*16 + lr][q*8]);
        #pragma unroll
        for (int ms = 0; ms < 4; ++ms)
            #pragma unroll
            for (int ns = 0; ns < 4; ++ns)
                acc[ms][ns] = __builtin_amdgcn_mfma_f32_16x16x32_bf16(
                                  af[ms], bf[ns], acc[ms][ns], 0,0,0);
        __syncthreads();
    }
    #pragma unroll
    for (int ms = 0; ms < 4; ++ms)
      #pragma unroll
      for (int ns = 0; ns < 4; ++ns) {
        int m = m0 + wm*64 + ms*16 + q*4;
        int n = n0 + wn*64 + ns*16 + lr;
        #pragma unroll
        for (int i = 0; i < 4; ++i)
            gi[(size_t)(m + i) * 3072 + n] = f2bf(acc[ms][ns][i]);
      }
}

// ---------------------------------------------------------------------------
// GRU recurrence v12 — v11's proven protocol + ballot-gated pipelined consume.
//
// Protocol identical to v11 (passed, exact): untagged u64 h quanta
// (single-copy atomic), producer publishes -> waitcnt ACK -> flag; the
// consumer-side flag gate doubles as overwrite safety.
//
// v12 consume: MFMA iteration it consumes runs {2it, 2it+1}, written exactly
// by producer blocks {2it, 2it+1}. Instead of (wait ALL flags) -> (64-load
// burst) -> (MFMA), poll flags once into a wave-uniform __ballot, then a
// fully-unrolled depth-4 software pipeline: per it, spin (usually free) on
// ballot bits 2it/2it+1, issue that pair's 2 loads, MFMA pair it-4.
//   - load issue overlaps MFMA (removes the serialized burst phase);
//   - a straggler producer blocks only the pipeline tail, not the whole
//     burst -> absorbs per-step max-of-64 jitter.
// Static indices via full unroll (runtime-indexed reg arrays -> scratch).
// hb4: [2][2][64][64] u64 = 128KiB (memset(0) = valid h0). flags [2][64].
// ---------------------------------------------------------------------------
__global__ __launch_bounds__(128, 1) void k_gru(
        const float* __restrict__ pad,   // [512][32]
        const short* __restrict__ gi,    // [16384][3072] bf16 (no bias)
        const short* __restrict__ Whht,  // [3072][1024] bf16
        const float* __restrict__ b_ih,  // [3072]
        const float* __restrict__ b_hh,  // [3072]
        unsigned long long* __restrict__ hb4,  // [2][2][64][64] u64 (zeroed)
        unsigned* __restrict__ flags,    // [2][64] step flags (pre-zeroed)
        float* __restrict__ out) {
    extern __shared__ short wlds[];      // 48 rows x 1024, stride 1032 shorts
    const int WS = 1032;
    int bid = blockIdx.x;                // 0..63
    int j0  = bid * 16;
    int tid = threadIdx.x;               // 0..127
    int w   = tid >> 6;                  // batch half
    int l   = tid & 63, lr = l & 15, q = l >> 4;

    // Stage weight slice: rows (gate g, col c) x 1024 shorts. (both waves)
    for (int idx = tid; idx < 48 * 128; idx += 128) {
        int row = idx >> 7;
        int ko  = (idx & 127) * 8;
        int g = row >> 4, c = row & 15;
        *reinterpret_cast<s8v*>(&wlds[(g * 16 + c) * WS + ko]) =
            *reinterpret_cast<const s8v*>(Whht + (size_t)(g * 1024 + j0 + c) * 1024 + ko);
    }
    __syncthreads();                     // weights ready; last sync in kernel

    int jq = j0 + q * 4;                 // first of this lane's 4 j-cols
    int b  = w * 16 + lr;                // this lane's batch row
    f4v sbr = *reinterpret_cast<const f4v*>(b_ih + jq)
            + *reinterpret_cast<const f4v*>(b_hh + jq);
    f4v sbz = *reinterpret_cast<const f4v*>(b_ih + 1024 + jq)
            + *reinterpret_cast<const f4v*>(b_hh + 1024 + jq);
    f4v sbn_i = *reinterpret_cast<const f4v*>(b_ih + 2048 + jq);
    f4v sbn_h = *reinterpret_cast<const f4v*>(b_hh + 2048 + jq);
    const short* w_r = &wlds[(0 * 16 + lr) * WS + q * 8];
    const short* w_z = &wlds[(1 * 16 + lr) * WS + q * 8];
    const short* w_n = &wlds[(2 * 16 + lr) * WS + q * 8];
    float hp[4] = {0.f, 0.f, 0.f, 0.f};

    const unsigned* myflag = flags + w * 64 + l;   // own-half flag of block l

    // Publish slot (loop-invariant except parity): col-group m = bid*4+q.
    int m_  = bid * 4 + q;
    int kk_ = ((m_ >> 3) << 1) | (m_ & 1);
    int sl_ = ((m_ & 7) >> 1) * 16 + lr;
    unsigned long long* hw0 = hb4 + (size_t)w * 4096 + kk_ * 64 + sl_;       // parity 0
    unsigned long long* hw1 = hw0 + 8192;                                    // parity 1
    // Consume base (parity 0/1): run k at base[k*64], lane-offset l.
    const unsigned long long* hc0 = hb4 + (size_t)w * 4096 + l;
    const unsigned long long* hc1 = hc0 + 8192;

    union u64s { unsigned long long u; short s[4]; };
    u64s gr_, gz_, gn_; float pv;
    {   // prefetch gi/pad for t=0
        const short* gp = gi + (size_t)b * 3072 + jq;
        gr_.u = *reinterpret_cast<const unsigned long long*>(gp);
        gz_.u = *reinterpret_cast<const unsigned long long*>(gp + 1024);
        gn_.u = *reinterpret_cast<const unsigned long long*>(gp + 2048);
        pv = pad[b];
    }

    for (int t = 0; t < 512; ++t) {
        unsigned uT = (unsigned)t;

        // ---- 1. single flag poll -> wave-uniform readiness ballot ----
        unsigned long long bal;
        {
            unsigned f = __hip_atomic_load(myflag, __ATOMIC_RELAXED,
                                           __HIP_MEMORY_SCOPE_AGENT);
            bal = __ballot((int)(f >= uT));
        }

        // ---- 2. depth-4 pipelined consume: spin(bits)->load pair->MFMA ----
        const unsigned long long* hbase = (t & 1) ? hc1 : hc0;
        unsigned long long ha[32], hb_[32];   // statically indexed (full unroll)
        f4v ar = {0,0,0,0}, az = {0,0,0,0}, an = {0,0,0,0};
        #pragma unroll
        for (int it = 0; it < 36; ++it) {
            if (it < 32) {
                unsigned long long need = 3ull << (2 * it);
                int g1 = 0;
                while ((bal & need) != need) {      // usually already set
                    if (++g1 > GUARD) break;        // anti-hang
                    __builtin_amdgcn_s_sleep(1);
                    unsigned f = __hip_atomic_load(myflag, __ATOMIC_RELAXED,
                                                   __HIP_MEMORY_SCOPE_AGENT);
                    bal = __ballot((int)(f >= uT));
                }
                ha[it]  = __hip_atomic_load(hbase + (2*it)     * 64,
                              __ATOMIC_RELAXED, __HIP_MEMORY_SCOPE_AGENT);
                hb_[it] = __hip_atomic_load(hbase + (2*it + 1) * 64,
                              __ATOMIC_RELAXED, __HIP_MEMORY_SCOPE_AGENT);
            }
            if (it >= 4) {
                int jt = it - 4;
                union { unsigned long long u[2]; s8v v; } hx;
                hx.u[0] = ha[jt]; hx.u[1] = hb_[jt];
                s8v r8 = *reinterpret_cast<const s8v*>(w_r + jt * 32);
                s8v z8 = *reinterpret_cast<const s8v*>(w_z + jt * 32);
                s8v n8 = *reinterpret_cast<const s8v*>(w_n + jt * 32);
                ar = __builtin_amdgcn_mfma_f32_16x16x32_bf16(r8, hx.v, ar, 0,0,0);
                az = __builtin_amdgcn_mfma_f32_16x16x32_bf16(z8, hx.v, az, 0,0,0);
                an = __builtin_amdgcn_mfma_f32_16x16x32_bf16(n8, hx.v, an, 0,0,0);
            }
        }

        // ---- 3. gates ----
        #pragma unroll
        for (int i = 0; i < 4; ++i) {
            float xr = bf2f(gr_.s[i]) + ar[i] + sbr[i];
            float xz = bf2f(gz_.s[i]) + az[i] + sbz[i];
            float r  = __builtin_amdgcn_rcpf(1.f + __expf(-xr));
            float z  = __builtin_amdgcn_rcpf(1.f + __expf(-xz));
            float xn = bf2f(gn_.s[i]) + sbn_i[i] + r * (an[i] + sbn_h[i]);
            float e2 = __expf(2.f * xn);
            float n  = 1.f - 2.f * __builtin_amdgcn_rcpf(1.f + e2);   // tanh
            float hnv = (1.f - z) * n + z * hp[i];
            hnv = pv * hp[i] + (1.f - pv) * hnv;
            hp[i] = hnv;
        }

        int rowg = t * 32 + b;

        // ---- 4. publish: h store -> ACK -> flag (prefetch not in flight) ----
        if (t < 511) {
            u64s pk;
            pk.s[0] = f2bf(hp[0]); pk.s[1] = f2bf(hp[1]);
            pk.s[2] = f2bf(hp[2]); pk.s[3] = f2bf(hp[3]);
            unsigned long long* hwr = ((t + 1) & 1) ? hw1 : hw0;
            __hip_atomic_store(hwr, pk.u, __ATOMIC_RELAXED, __HIP_MEMORY_SCOPE_AGENT);
            __builtin_amdgcn_s_waitcnt(0);       // h store visible at L3
            if (l == 0)
                __hip_atomic_store(flags + w * 64 + bid, (unsigned)(t + 1),
                                   __ATOMIC_RELAXED, __HIP_MEMORY_SCOPE_AGENT);
        }

        // ---- 5. out stores after the flag — drain overlaps next poll ----
        float4 o4 = { hp[0], hp[1], hp[2], hp[3] };
        *reinterpret_cast<float4*>(out + (size_t)rowg * 1024 + jq) = o4;
        if (t == 511) {
            *reinterpret_cast<float4*>(out + 16777216 + b * 1024 + jq) = o4;
            *reinterpret_cast<float4*>(out + 16809984 + b * 1024 + jq) = o4;
        }

        // ---- 6. gi/pad prefetch for t+1, AFTER publish (off ACK path) ----
        if (t < 511) {
            const short* gp = gi + (size_t)((t + 1) * 32 + b) * 3072 + jq;
            gr_.u = *reinterpret_cast<const unsigned long long*>(gp);
            gz_.u = *reinterpret_cast<const unsigned long long*>(gp + 1024);
            gn_.u = *reinterpret_cast<const unsigned long long*>(gp + 2048);
            pv = pad[(t + 1) * 32 + b];
        }
    }
}

// ---------------------------------------------------------------------------
extern "C" void kernel_launch(void* const* d_in, const int* in_sizes, int n_in,
                              void* d_out, int out_size, void* d_ws, size_t ws_size,
                              hipStream_t stream) {
    const float* X   = (const float*)d_in[0];
    const float* pad = (const float*)d_in[1];
    const float* Wih = (const float*)d_in[2];
    const float* Whh = (const float*)d_in[3];
    const float* bih = (const float*)d_in[4];
    const float* bhh = (const float*)d_in[5];
    float* out = (float*)d_out;

    char* ws = (char*)d_ws;
    short*    gi    = (short*)(ws);                      // 100,663,296 B
    short*    Wih_t = (short*)(ws + 100663296);          //   6,291,456 B (dead after gemm)
    short*    Whh_t = (short*)(ws + 106954752);          //   6,291,456 B
    unsigned long long* hb4 =
        (unsigned long long*)(ws + 100663296);           // reuses Wih_t: 131,072 B
    unsigned* flags = (unsigned*)(ws + 100663296 + 131072);  // 512 B

    hipLaunchKernelGGL(k_transpose_bf16, dim3(1536), dim3(256), 0, stream, Wih, Wih_t);
    hipLaunchKernelGGL(k_transpose_bf16, dim3(1536), dim3(256), 0, stream, Whh, Whh_t);
    hipLaunchKernelGGL(k_gemm_gi, dim3(128 * 24), dim3(256), 0, stream, X, Wih_t, gi);

    // Zero the h buffer (h0 = 0) + flags. Enqueued AFTER the gemm so the
    // Wih_t aliasing is stream-safe.
    hipMemsetAsync(hb4, 0, 131072 + 512, stream);

    hipFuncSetAttribute((const void*)k_gru,
                        hipFuncAttributeMaxDynamicSharedMemorySize, 99072);
    hipLaunchKernelGGL(k_gru, dim3(NB), dim3(128), 99072, stream,
                       pad, gi, Whh_t, bih, bhh, hb4, flags, out);
}

// Round 10
// 2677.726 us; speedup vs baseline: 1.0490x; 1.0490x over previous
//
#include <hip/hip_runtime.h>
#include <cmath>

// T=512, B=32, D=1024, H=1024, 3H=3072
// d_out: outputs (512*32*1024) ++ outputs[-1] (32*1024) ++ h_last (32*1024)  fp32

typedef short s8v  __attribute__((ext_vector_type(8)));   // 8 x bf16 (raw bits)
typedef float f4v  __attribute__((ext_vector_type(4)));   // MFMA accumulator

#define NB 64       // blocks in the GRU grid
#define GUARD 16384 // bounded-spin: degrade to wrong-answer instead of hanging

__device__ __forceinline__ short f2bf(float f) {
    return __builtin_bit_cast(short, (__bf16)f);          // RNE convert
}
__device__ __forceinline__ float bf2f(short s) {
    return (float)__builtin_bit_cast(__bf16, s);
}

// ---------------------------------------------------------------------------
// Transpose W [1024][3072] fp32  ->  Wt [3072][1024] bf16.
// ---------------------------------------------------------------------------
__global__ __launch_bounds__(256) void k_transpose_bf16(
        const float* __restrict__ W, short* __restrict__ Wt) {
    __shared__ short Ls[32][72];
    int bk = blockIdx.x & 31;
    int bn = blockIdx.x >> 5;
    int k0 = bk * 32, n0 = bn * 64;
    int tid = threadIdx.x;
    {
        int r  = tid >> 3;
        int c0 = (tid & 7) * 8;
        const float* src = W + (size_t)(k0 + r) * 3072 + n0 + c0;
        float4 f0 = *reinterpret_cast<const float4*>(src);
        float4 f1 = *reinterpret_cast<const float4*>(src + 4);
        Ls[r][c0+0] = f2bf(f0.x); Ls[r][c0+1] = f2bf(f0.y);
        Ls[r][c0+2] = f2bf(f0.z); Ls[r][c0+3] = f2bf(f0.w);
        Ls[r][c0+4] = f2bf(f1.x); Ls[r][c0+5] = f2bf(f1.y);
        Ls[r][c0+6] = f2bf(f1.z); Ls[r][c0+7] = f2bf(f1.w);
    }
    __syncthreads();
    {
        int j   = tid >> 2;
        int kk0 = (tid & 3) * 8;
        s8v v;
        #pragma unroll
        for (int s = 0; s < 8; ++s) v[s] = Ls[kk0 + s][j];
        *reinterpret_cast<s8v*>(Wt + (size_t)(n0 + j) * 1024 + k0 + kk0) = v;
    }
}

// ---------------------------------------------------------------------------
// gi = X @ W_ih.  M=16384, N=3072, K=1024.  Output bf16.
// 128x128 tile, 4 waves, 4x4 16x16 frags/wave (verified in v12, −155us).
// ---------------------------------------------------------------------------
__global__ __launch_bounds__(256) void k_gemm_gi(
        const float* __restrict__ X, const short* __restrict__ Wt,
        short* __restrict__ gi) {
    __shared__ short As[128][40];
    __shared__ short Bs[128][40];
    int bm = blockIdx.x & 127;           // 128 m-blocks x 128 rows
    int bn = blockIdx.x >> 7;            // 24 n-blocks x 128 cols
    int m0 = bm * 128, n0 = bn * 128;
    int tid = threadIdx.x;
    int wid = tid >> 6, l = tid & 63;
    int wm = wid >> 1, wn = wid & 1;     // wave quadrant (64x64 each)
    int lr = l & 15, q = l >> 4;
    f4v acc[4][4] = {};
    int sr = tid >> 1;                   // 0..127 staging row
    int sc = (tid & 1) * 16;             // 0 or 16

    for (int kc = 0; kc < 1024; kc += 32) {
        const float* asrc = X + (size_t)(m0 + sr) * 1024 + kc + sc;
        float4 f0 = *reinterpret_cast<const float4*>(asrc);
        float4 f1 = *reinterpret_cast<const float4*>(asrc + 4);
        float4 f2 = *reinterpret_cast<const float4*>(asrc + 8);
        float4 f3 = *reinterpret_cast<const float4*>(asrc + 12);
        s8v av0, av1;
        av0[0]=f2bf(f0.x); av0[1]=f2bf(f0.y); av0[2]=f2bf(f0.z); av0[3]=f2bf(f0.w);
        av0[4]=f2bf(f1.x); av0[5]=f2bf(f1.y); av0[6]=f2bf(f1.z); av0[7]=f2bf(f1.w);
        av1[0]=f2bf(f2.x); av1[1]=f2bf(f2.y); av1[2]=f2bf(f2.z); av1[3]=f2bf(f2.w);
        av1[4]=f2bf(f3.x); av1[5]=f2bf(f3.y); av1[6]=f2bf(f3.z); av1[7]=f2bf(f3.w);
        *reinterpret_cast<s8v*>(&As[sr][sc])     = av0;
        *reinterpret_cast<s8v*>(&As[sr][sc + 8]) = av1;
        const short* bsrc = Wt + (size_t)(n0 + sr) * 1024 + kc + sc;
        *reinterpret_cast<s8v*>(&Bs[sr][sc])     = *reinterpret_cast<const s8v*>(bsrc);
        *reinterpret_cast<s8v*>(&Bs[sr][sc + 8]) = *reinterpret_cast<const s8v*>(bsrc + 8);
        __syncthreads();
        s8v af[4], bf[4];
        #pragma unroll
        for (int ms = 0; ms < 4; ++ms)
            af[ms] = *reinterpret_cast<const s8v*>(&As[wm*64 + ms*16 + lr][q*8]);
        #pragma unroll
        for (int ns = 0; ns < 4; ++ns)
            bf[ns] = *reinterpret_cast<const s8v*>(&Bs[wn*64 + ns*16 + lr][q*8]);
        #pragma unroll
        for (int ms = 0; ms < 4; ++ms)
            #pragma unroll
            for (int ns = 0; ns < 4; ++ns)
                acc[ms][ns] = __builtin_amdgcn_mfma_f32_16x16x32_bf16(
                                  af[ms], bf[ns], acc[ms][ns], 0,0,0);
        __syncthreads();
    }
    #pragma unroll
    for (int ms = 0; ms < 4; ++ms)
      #pragma unroll
      for (int ns = 0; ns < 4; ++ns) {
        int m = m0 + wm*64 + ms*16 + q*4;
        int n = n0 + wn*64 + ns*16 + lr;
        #pragma unroll
        for (int i = 0; i < 4; ++i)
            gi[(size_t)(m + i) * 3072 + n] = f2bf(acc[ms][ns][i]);
      }
}

// ---------------------------------------------------------------------------
// GRU recurrence v13 — v11's proven burst consume + merged ACK/detect RT.
//
// v12 lesson: gating loads on readiness capped MLP at 8 outstanding loads
// (8 serialized RTs). v11's 64-wide burst (1 RT) restored here verbatim.
//
// New: the producer-side ACK (h-store drain) and the first detect poll for
// step t+1 were two back-to-back independent L3 RTs. v13 issues the h store
// AND the flag-snapshot load together, drains both with ONE waitcnt(0),
// raises the flag, then checks the snapshot with own-lane exemption
// (f >= t+1 || l == bid). If other producers already published, detect
// costs zero extra RT. Detect thus lives at the END of iteration t; the
// burst at iteration t+1 starts unconditionally.
//
// Safety (v11 induction, relocated): flag j = t+1 is raised only after wave
// j's burst-of-t completed (waitcnt before MFMA), so our end-of-t detect
// (all own-half flags >= t+1) implies all readers of h(t) finished before
// we overwrite that parity with h(t+2) at iter t+1. Flag raise precedes
// the spin -> no circular wait. t=0: buffer pre-zeroed, no detect needed.
// hb4: [2][2][64][64] u64 = 128KiB (memset(0) = valid h0). flags [2][64].
// ---------------------------------------------------------------------------
__global__ __launch_bounds__(128, 1) void k_gru(
        const float* __restrict__ pad,   // [512][32]
        const short* __restrict__ gi,    // [16384][3072] bf16 (no bias)
        const short* __restrict__ Whht,  // [3072][1024] bf16
        const float* __restrict__ b_ih,  // [3072]
        const float* __restrict__ b_hh,  // [3072]
        unsigned long long* __restrict__ hb4,  // [2][2][64][64] u64 (zeroed)
        unsigned* __restrict__ flags,    // [2][64] step flags (pre-zeroed)
        float* __restrict__ out) {
    extern __shared__ short wlds[];      // 48 rows x 1024, stride 1032 shorts
    const int WS = 1032;
    int bid = blockIdx.x;                // 0..63
    int j0  = bid * 16;
    int tid = threadIdx.x;               // 0..127
    int w   = tid >> 6;                  // batch half
    int l   = tid & 63, lr = l & 15, q = l >> 4;

    // Stage weight slice: rows (gate g, col c) x 1024 shorts. (both waves)
    for (int idx = tid; idx < 48 * 128; idx += 128) {
        int row = idx >> 7;
        int ko  = (idx & 127) * 8;
        int g = row >> 4, c = row & 15;
        *reinterpret_cast<s8v*>(&wlds[(g * 16 + c) * WS + ko]) =
            *reinterpret_cast<const s8v*>(Whht + (size_t)(g * 1024 + j0 + c) * 1024 + ko);
    }
    __syncthreads();                     // weights ready; last sync in kernel

    int jq = j0 + q * 4;                 // first of this lane's 4 j-cols
    int b  = w * 16 + lr;                // this lane's batch row
    f4v sbr = *reinterpret_cast<const f4v*>(b_ih + jq)
            + *reinterpret_cast<const f4v*>(b_hh + jq);
    f4v sbz = *reinterpret_cast<const f4v*>(b_ih + 1024 + jq)
            + *reinterpret_cast<const f4v*>(b_hh + 1024 + jq);
    f4v sbn_i = *reinterpret_cast<const f4v*>(b_ih + 2048 + jq);
    f4v sbn_h = *reinterpret_cast<const f4v*>(b_hh + 2048 + jq);
    const short* w_r = &wlds[(0 * 16 + lr) * WS + q * 8];
    const short* w_z = &wlds[(1 * 16 + lr) * WS + q * 8];
    const short* w_n = &wlds[(2 * 16 + lr) * WS + q * 8];
    float hp[4] = {0.f, 0.f, 0.f, 0.f};

    const unsigned* myflag = flags + w * 64 + l;   // own-half flag of block l
    int self = (int)(l == (unsigned)bid);          // own-lane exemption

    // Publish slot (loop-invariant except parity): col-group m = bid*4+q.
    int m_  = bid * 4 + q;
    int kk_ = ((m_ >> 3) << 1) | (m_ & 1);
    int sl_ = ((m_ & 7) >> 1) * 16 + lr;
    unsigned long long* hw0 = hb4 + (size_t)w * 4096 + kk_ * 64 + sl_;       // parity 0
    unsigned long long* hw1 = hw0 + 8192;                                    // parity 1
    // Consume base (parity 0/1): run k at base[k*64], lane-offset l.
    const unsigned long long* hc0 = hb4 + (size_t)w * 4096 + l;
    const unsigned long long* hc1 = hc0 + 8192;

    union u64s { unsigned long long u; short s[4]; };
    u64s gr_, gz_, gn_; float pv;
    {   // prefetch gi/pad for t=0
        const short* gp = gi + (size_t)b * 3072 + jq;
        gr_.u = *reinterpret_cast<const unsigned long long*>(gp);
        gz_.u = *reinterpret_cast<const unsigned long long*>(gp + 1024);
        gn_.u = *reinterpret_cast<const unsigned long long*>(gp + 2048);
        pv = pad[b];
    }

    for (int t = 0; t < 512; ++t) {
        // ---- 1. burst: 64 u64 loads (full MLP, one RT), no gating ----
        //       readiness for step t was established at end of step t-1.
        const unsigned long long* hbase = (t & 1) ? hc1 : hc0;
        unsigned long long hreg[64];
        #pragma unroll
        for (int k = 0; k < 64; ++k)
            hreg[k] = __hip_atomic_load(hbase + (size_t)k * 64,
                                        __ATOMIC_RELAXED, __HIP_MEMORY_SCOPE_AGENT);

        // ---- 2. MFMA consume ----
        f4v ar = {0,0,0,0}, az = {0,0,0,0}, an = {0,0,0,0};
        #pragma unroll
        for (int it = 0; it < 32; ++it) {
            union { unsigned long long u[2]; s8v v; } hx;
            hx.u[0] = hreg[2*it]; hx.u[1] = hreg[2*it+1];
            s8v r8 = *reinterpret_cast<const s8v*>(w_r + it * 32);
            s8v z8 = *reinterpret_cast<const s8v*>(w_z + it * 32);
            s8v n8 = *reinterpret_cast<const s8v*>(w_n + it * 32);
            ar = __builtin_amdgcn_mfma_f32_16x16x32_bf16(r8, hx.v, ar, 0,0,0);
            az = __builtin_amdgcn_mfma_f32_16x16x32_bf16(z8, hx.v, az, 0,0,0);
            an = __builtin_amdgcn_mfma_f32_16x16x32_bf16(n8, hx.v, an, 0,0,0);
        }

        // ---- 3. gates ----
        #pragma unroll
        for (int i = 0; i < 4; ++i) {
            float xr = bf2f(gr_.s[i]) + ar[i] + sbr[i];
            float xz = bf2f(gz_.s[i]) + az[i] + sbz[i];
            float r  = __builtin_amdgcn_rcpf(1.f + __expf(-xr));
            float z  = __builtin_amdgcn_rcpf(1.f + __expf(-xz));
            float xn = bf2f(gn_.s[i]) + sbn_i[i] + r * (an[i] + sbn_h[i]);
            float e2 = __expf(2.f * xn);
            float n  = 1.f - 2.f * __builtin_amdgcn_rcpf(1.f + e2);   // tanh
            float hnv = (1.f - z) * n + z * hp[i];
            hnv = pv * hp[i] + (1.f - pv) * hnv;
            hp[i] = hnv;
        }

        int rowg = t * 32 + b;
        float4 o4 = { hp[0], hp[1], hp[2], hp[3] };

        if (t < 511) {
            unsigned uT1 = (unsigned)(t + 1);

            // ---- 4. publish + merged ACK/detect: h store and flag-snapshot
            //         load drain together under ONE waitcnt (one RT). ----
            u64s pk;
            pk.s[0] = f2bf(hp[0]); pk.s[1] = f2bf(hp[1]);
            pk.s[2] = f2bf(hp[2]); pk.s[3] = f2bf(hp[3]);
            unsigned long long* hwr = ((t + 1) & 1) ? hw1 : hw0;
            __hip_atomic_store(hwr, pk.u, __ATOMIC_RELAXED, __HIP_MEMORY_SCOPE_AGENT);
            unsigned fsnap = __hip_atomic_load(myflag, __ATOMIC_RELAXED,
                                               __HIP_MEMORY_SCOPE_AGENT);
            __builtin_amdgcn_s_waitcnt(0);       // drains h store AND snapshot
            if (l == 0)
                __hip_atomic_store(flags + w * 64 + bid, uT1,
                                   __ATOMIC_RELAXED, __HIP_MEMORY_SCOPE_AGENT);

            // ---- 5. out stores + gi/pad prefetch (drain under the spin) ----
            *reinterpret_cast<float4*>(out + (size_t)rowg * 1024 + jq) = o4;
            {
                const short* gp = gi + (size_t)((t + 1) * 32 + b) * 3072 + jq;
                gr_.u = *reinterpret_cast<const unsigned long long*>(gp);
                gz_.u = *reinterpret_cast<const unsigned long long*>(gp + 1024);
                gn_.u = *reinterpret_cast<const unsigned long long*>(gp + 2048);
                pv = pad[(t + 1) * 32 + b];
            }

            // ---- 6. detect for t+1: snapshot first (often free), then poll.
            //         Own lane exempt (our flag is known-raised). ----
            int ok = (int)(fsnap >= uT1) | self;
            int g1 = 0;
            while (!__all(ok)) {
                if (++g1 > GUARD) break;         // anti-hang: degrade, don't die
                __builtin_amdgcn_s_sleep(1);
                unsigned f = __hip_atomic_load(myflag, __ATOMIC_RELAXED,
                                               __HIP_MEMORY_SCOPE_AGENT);
                ok = (int)(f >= uT1) | self;
            }
        } else {
            // t == 511: no publish; final out stores.
            *reinterpret_cast<float4*>(out + (size_t)rowg * 1024 + jq) = o4;
            *reinterpret_cast<float4*>(out + 16777216 + b * 1024 + jq) = o4;
            *reinterpret_cast<float4*>(out + 16809984 + b * 1024 + jq) = o4;
        }
    }
}

// ---------------------------------------------------------------------------
extern "C" void kernel_launch(void* const* d_in, const int* in_sizes, int n_in,
                              void* d_out, int out_size, void* d_ws, size_t ws_size,
                              hipStream_t stream) {
    const float* X   = (const float*)d_in[0];
    const float* pad = (const float*)d_in[1];
    const float* Wih = (const float*)d_in[2];
    const float* Whh = (const float*)d_in[3];
    const float* bih = (const float*)d_in[4];
    const float* bhh = (const float*)d_in[5];
    float* out = (float*)d_out;

    char* ws = (char*)d_ws;
    short*    gi    = (short*)(ws);                      // 100,663,296 B
    short*    Wih_t = (short*)(ws + 100663296);          //   6,291,456 B (dead after gemm)
    short*    Whh_t = (short*)(ws + 106954752);          //   6,291,456 B
    unsigned long long* hb4 =
        (unsigned long long*)(ws + 100663296);           // reuses Wih_t: 131,072 B
    unsigned* flags = (unsigned*)(ws + 100663296 + 131072);  // 512 B

    hipLaunchKernelGGL(k_transpose_bf16, dim3(1536), dim3(256), 0, stream, Wih, Wih_t);
    hipLaunchKernelGGL(k_transpose_bf16, dim3(1536), dim3(256), 0, stream, Whh, Whh_t);
    hipLaunchKernelGGL(k_gemm_gi, dim3(128 * 24), dim3(256), 0, stream, X, Wih_t, gi);

    // Zero the h buffer (h0 = 0) + flags. Enqueued AFTER the gemm so the
    // Wih_t aliasing is stream-safe.
    hipMemsetAsync(hb4, 0, 131072 + 512, stream);

    hipFuncSetAttribute((const void*)k_gru,
                        hipFuncAttributeMaxDynamicSharedMemorySize, 99072);
    hipLaunchKernelGGL(k_gru, dim3(NB), dim3(128), 99072, stream,
                       pad, gi, Whh_t, bih, bhh, hb4, flags, out);
}

// Round 11
// 2407.983 us; speedup vs baseline: 1.1665x; 1.1120x over previous
//
#include <hip/hip_runtime.h>
#include <cmath>

// T=512, B=32, D=1024, H=1024, 3H=3072
// d_out: outputs (512*32*1024) ++ outputs[-1] (32*1024) ++ h_last (32*1024)  fp32

typedef short s8v  __attribute__((ext_vector_type(8)));   // 8 x bf16 (raw bits)
typedef float f4v  __attribute__((ext_vector_type(4)));   // MFMA accumulator

#define NB 64       // blocks in the GRU grid
#define GUARD 16384 // bounded-spin: degrade to wrong-answer instead of hanging

__device__ __forceinline__ short f2bf(float f) {
    return __builtin_bit_cast(short, (__bf16)f);          // RNE convert
}
__device__ __forceinline__ float bf2f(short s) {
    return (float)__builtin_bit_cast(__bf16, s);
}

// ---------------------------------------------------------------------------
// Transpose W [1024][3072] fp32  ->  Wt [3072][1024] bf16.
// ---------------------------------------------------------------------------
__global__ __launch_bounds__(256) void k_transpose_bf16(
        const float* __restrict__ W, short* __restrict__ Wt) {
    __shared__ short Ls[32][72];
    int bk = blockIdx.x & 31;
    int bn = blockIdx.x >> 5;
    int k0 = bk * 32, n0 = bn * 64;
    int tid = threadIdx.x;
    {
        int r  = tid >> 3;
        int c0 = (tid & 7) * 8;
        const float* src = W + (size_t)(k0 + r) * 3072 + n0 + c0;
        float4 f0 = *reinterpret_cast<const float4*>(src);
        float4 f1 = *reinterpret_cast<const float4*>(src + 4);
        Ls[r][c0+0] = f2bf(f0.x); Ls[r][c0+1] = f2bf(f0.y);
        Ls[r][c0+2] = f2bf(f0.z); Ls[r][c0+3] = f2bf(f0.w);
        Ls[r][c0+4] = f2bf(f1.x); Ls[r][c0+5] = f2bf(f1.y);
        Ls[r][c0+6] = f2bf(f1.z); Ls[r][c0+7] = f2bf(f1.w);
    }
    __syncthreads();
    {
        int j   = tid >> 2;
        int kk0 = (tid & 3) * 8;
        s8v v;
        #pragma unroll
        for (int s = 0; s < 8; ++s) v[s] = Ls[kk0 + s][j];
        *reinterpret_cast<s8v*>(Wt + (size_t)(n0 + j) * 1024 + k0 + kk0) = v;
    }
}

// ---------------------------------------------------------------------------
// gi = X @ W_ih.  M=16384, N=3072, K=1024.  Output bf16.
// 128x128 tile, 4 waves, 4x4 16x16 frags/wave (verified v12/v13, −155us,
// gi bitwise identical to the 64x64 original).
// ---------------------------------------------------------------------------
__global__ __launch_bounds__(256) void k_gemm_gi(
        const float* __restrict__ X, const short* __restrict__ Wt,
        short* __restrict__ gi) {
    __shared__ short As[128][40];
    __shared__ short Bs[128][40];
    int bm = blockIdx.x & 127;           // 128 m-blocks x 128 rows
    int bn = blockIdx.x >> 7;            // 24 n-blocks x 128 cols
    int m0 = bm * 128, n0 = bn * 128;
    int tid = threadIdx.x;
    int wid = tid >> 6, l = tid & 63;
    int wm = wid >> 1, wn = wid & 1;     // wave quadrant (64x64 each)
    int lr = l & 15, q = l >> 4;
    f4v acc[4][4] = {};
    int sr = tid >> 1;                   // 0..127 staging row
    int sc = (tid & 1) * 16;             // 0 or 16

    for (int kc = 0; kc < 1024; kc += 32) {
        const float* asrc = X + (size_t)(m0 + sr) * 1024 + kc + sc;
        float4 f0 = *reinterpret_cast<const float4*>(asrc);
        float4 f1 = *reinterpret_cast<const float4*>(asrc + 4);
        float4 f2 = *reinterpret_cast<const float4*>(asrc + 8);
        float4 f3 = *reinterpret_cast<const float4*>(asrc + 12);
        s8v av0, av1;
        av0[0]=f2bf(f0.x); av0[1]=f2bf(f0.y); av0[2]=f2bf(f0.z); av0[3]=f2bf(f0.w);
        av0[4]=f2bf(f1.x); av0[5]=f2bf(f1.y); av0[6]=f2bf(f1.z); av0[7]=f2bf(f1.w);
        av1[0]=f2bf(f2.x); av1[1]=f2bf(f2.y); av1[2]=f2bf(f2.z); av1[3]=f2bf(f2.w);
        av1[4]=f2bf(f3.x); av1[5]=f2bf(f3.y); av1[6]=f2bf(f3.z); av1[7]=f2bf(f3.w);
        *reinterpret_cast<s8v*>(&As[sr][sc])     = av0;
        *reinterpret_cast<s8v*>(&As[sr][sc + 8]) = av1;
        const short* bsrc = Wt + (size_t)(n0 + sr) * 1024 + kc + sc;
        *reinterpret_cast<s8v*>(&Bs[sr][sc])     = *reinterpret_cast<const s8v*>(bsrc);
        *reinterpret_cast<s8v*>(&Bs[sr][sc + 8]) = *reinterpret_cast<const s8v*>(bsrc + 8);
        __syncthreads();
        s8v af[4], bf[4];
        #pragma unroll
        for (int ms = 0; ms < 4; ++ms)
            af[ms] = *reinterpret_cast<const s8v*>(&As[wm*64 + ms*16 + lr][q*8]);
        #pragma unroll
        for (int ns = 0; ns < 4; ++ns)
            bf[ns] = *reinterpret_cast<const s8v*>(&Bs[wn*64 + ns*16 + lr][q*8]);
        #pragma unroll
        for (int ms = 0; ms < 4; ++ms)
            #pragma unroll
            for (int ns = 0; ns < 4; ++ns)
                acc[ms][ns] = __builtin_amdgcn_mfma_f32_16x16x32_bf16(
                                  af[ms], bf[ns], acc[ms][ns], 0,0,0);
        __syncthreads();
    }
    #pragma unroll
    for (int ms = 0; ms < 4; ++ms)
      #pragma unroll
      for (int ns = 0; ns < 4; ++ns) {
        int m = m0 + wm*64 + ms*16 + q*4;
        int n = n0 + wn*64 + ns*16 + lr;
        #pragma unroll
        for (int i = 0; i < 4; ++i)
            gi[(size_t)(m + i) * 3072 + n] = f2bf(acc[ms][ns][i]);
      }
}

// ---------------------------------------------------------------------------
// GRU recurrence v14 == v11 (measured best: 2087us, 4.08us/step) + schedule
// pins. Thirteen variants establish v11's structure as the optimum:
//   flag-wait (own half) -> 64-wide u64 burst (full MLP, coalesced layout)
//   -> MFMA -> gates -> publish: h-store -> waitcnt ACK -> flag
//   -> out stores -> gi/pad prefetch LAST (nothing HBM in flight at ACK).
// v13's regression (+0.74us/step) is attributed to the scheduler mixing the
// HBM prefetch into the ACK window once the code around it moved; two
// sched_barrier(0) pins now make the measured-good order structural:
//   pin A after the ACK waitcnt (nothing below may hoist above the drain),
//   pin B after the flag store (out/prefetch may not move above the flag).
// Protocol safety (v11 induction): flag j >= t  <=>  wave j consumed t-1;
// h(t+2) overwrites t-parity only after all own-half flags >= t+1; a wave
// still reading t has flag <= t. Untagged u64 quanta are single-copy atomic.
// hb4: [2][2][64][64] u64 = 128KiB (memset(0) = valid h0). flags [2][64].
// ---------------------------------------------------------------------------
__global__ __launch_bounds__(128, 1) void k_gru(
        const float* __restrict__ pad,   // [512][32]
        const short* __restrict__ gi,    // [16384][3072] bf16 (no bias)
        const short* __restrict__ Whht,  // [3072][1024] bf16
        const float* __restrict__ b_ih,  // [3072]
        const float* __restrict__ b_hh,  // [3072]
        unsigned long long* __restrict__ hb4,  // [2][2][64][64] u64 (zeroed)
        unsigned* __restrict__ flags,    // [2][64] step flags (pre-zeroed)
        float* __restrict__ out) {
    extern __shared__ short wlds[];      // 48 rows x 1024, stride 1032 shorts
    const int WS = 1032;
    int bid = blockIdx.x;                // 0..63
    int j0  = bid * 16;
    int tid = threadIdx.x;               // 0..127
    int w   = tid >> 6;                  // batch half
    int l   = tid & 63, lr = l & 15, q = l >> 4;

    // Stage weight slice: rows (gate g, col c) x 1024 shorts. (both waves)
    for (int idx = tid; idx < 48 * 128; idx += 128) {
        int row = idx >> 7;
        int ko  = (idx & 127) * 8;
        int g = row >> 4, c = row & 15;
        *reinterpret_cast<s8v*>(&wlds[(g * 16 + c) * WS + ko]) =
            *reinterpret_cast<const s8v*>(Whht + (size_t)(g * 1024 + j0 + c) * 1024 + ko);
    }
    __syncthreads();                     // weights ready; last sync in kernel

    int jq = j0 + q * 4;                 // first of this lane's 4 j-cols
    int b  = w * 16 + lr;                // this lane's batch row
    f4v sbr = *reinterpret_cast<const f4v*>(b_ih + jq)
            + *reinterpret_cast<const f4v*>(b_hh + jq);
    f4v sbz = *reinterpret_cast<const f4v*>(b_ih + 1024 + jq)
            + *reinterpret_cast<const f4v*>(b_hh + 1024 + jq);
    f4v sbn_i = *reinterpret_cast<const f4v*>(b_ih + 2048 + jq);
    f4v sbn_h = *reinterpret_cast<const f4v*>(b_hh + 2048 + jq);
    const short* w_r = &wlds[(0 * 16 + lr) * WS + q * 8];
    const short* w_z = &wlds[(1 * 16 + lr) * WS + q * 8];
    const short* w_n = &wlds[(2 * 16 + lr) * WS + q * 8];
    float hp[4] = {0.f, 0.f, 0.f, 0.f};

    const unsigned* myflag = flags + w * 64 + l;   // own-half flag of block l

    // Publish slot (loop-invariant except parity): col-group m = bid*4+q.
    int m_  = bid * 4 + q;
    int kk_ = ((m_ >> 3) << 1) | (m_ & 1);
    int sl_ = ((m_ & 7) >> 1) * 16 + lr;
    unsigned long long* hw0 = hb4 + (size_t)w * 4096 + kk_ * 64 + sl_;       // parity 0
    unsigned long long* hw1 = hw0 + 8192;                                    // parity 1
    // Consume base (parity 0/1): run k at base[k*64], lane-offset l.
    const unsigned long long* hc0 = hb4 + (size_t)w * 4096 + l;
    const unsigned long long* hc1 = hc0 + 8192;

    union u64s { unsigned long long u; short s[4]; };
    u64s gr_, gz_, gn_; float pv;
    {   // prefetch gi/pad for t=0
        const short* gp = gi + (size_t)b * 3072 + jq;
        gr_.u = *reinterpret_cast<const unsigned long long*>(gp);
        gz_.u = *reinterpret_cast<const unsigned long long*>(gp + 1024);
        gn_.u = *reinterpret_cast<const unsigned long long*>(gp + 2048);
        pv = pad[b];
    }

    for (int t = 0; t < 512; ++t) {
        // ---- 1. flag wait (own half only): detect + overwrite-safety ----
        if (t) {
            unsigned uT = (unsigned)t;
            int g1 = 0;
            for (;;) {
                unsigned f = __hip_atomic_load(myflag, __ATOMIC_RELAXED,
                                               __HIP_MEMORY_SCOPE_AGENT);
                if (__all((int)(f >= uT))) break;
                if (++g1 > GUARD) break;     // anti-hang: degrade, don't die
                __builtin_amdgcn_s_sleep(1);
            }
        }

        // ---- 2. burst: 64 u64 loads, each instr = contiguous 512B ----
        const unsigned long long* hbase = (t & 1) ? hc1 : hc0;
        unsigned long long hreg[64];
        #pragma unroll
        for (int k = 0; k < 64; ++k)
            hreg[k] = __hip_atomic_load(hbase + (size_t)k * 64,
                                        __ATOMIC_RELAXED, __HIP_MEMORY_SCOPE_AGENT);

        // ---- 3. MFMA consume ----
        f4v ar = {0,0,0,0}, az = {0,0,0,0}, an = {0,0,0,0};
        #pragma unroll
        for (int it = 0; it < 32; ++it) {
            union { unsigned long long u[2]; s8v v; } hx;
            hx.u[0] = hreg[2*it]; hx.u[1] = hreg[2*it+1];
            s8v r8 = *reinterpret_cast<const s8v*>(w_r + it * 32);
            s8v z8 = *reinterpret_cast<const s8v*>(w_z + it * 32);
            s8v n8 = *reinterpret_cast<const s8v*>(w_n + it * 32);
            ar = __builtin_amdgcn_mfma_f32_16x16x32_bf16(r8, hx.v, ar, 0,0,0);
            az = __builtin_amdgcn_mfma_f32_16x16x32_bf16(z8, hx.v, az, 0,0,0);
            an = __builtin_amdgcn_mfma_f32_16x16x32_bf16(n8, hx.v, an, 0,0,0);
        }

        // ---- 4. gates ----
        #pragma unroll
        for (int i = 0; i < 4; ++i) {
            float xr = bf2f(gr_.s[i]) + ar[i] + sbr[i];
            float xz = bf2f(gz_.s[i]) + az[i] + sbz[i];
            float r  = __builtin_amdgcn_rcpf(1.f + __expf(-xr));
            float z  = __builtin_amdgcn_rcpf(1.f + __expf(-xz));
            float xn = bf2f(gn_.s[i]) + sbn_i[i] + r * (an[i] + sbn_h[i]);
            float e2 = __expf(2.f * xn);
            float n  = 1.f - 2.f * __builtin_amdgcn_rcpf(1.f + e2);   // tanh
            float hnv = (1.f - z) * n + z * hp[i];
            hnv = pv * hp[i] + (1.f - pv) * hnv;
            hp[i] = hnv;
        }

        int rowg = t * 32 + b;

        // ---- 5. publish: h store -> ACK -> flag. Pins A/B keep the HBM
        //         out/prefetch traffic strictly BELOW the drain + flag. ----
        if (t < 511) {
            u64s pk;
            pk.s[0] = f2bf(hp[0]); pk.s[1] = f2bf(hp[1]);
            pk.s[2] = f2bf(hp[2]); pk.s[3] = f2bf(hp[3]);
            unsigned long long* hwr = ((t + 1) & 1) ? hw1 : hw0;
            __hip_atomic_store(hwr, pk.u, __ATOMIC_RELAXED, __HIP_MEMORY_SCOPE_AGENT);
            __builtin_amdgcn_s_waitcnt(0);       // h store visible at L3
            __builtin_amdgcn_sched_barrier(0);   // pin A: nothing hoists above drain
            if (l == 0)
                __hip_atomic_store(flags + w * 64 + bid, (unsigned)(t + 1),
                                   __ATOMIC_RELAXED, __HIP_MEMORY_SCOPE_AGENT);
            __builtin_amdgcn_sched_barrier(0);   // pin B: out/prefetch stay below flag
        }

        // ---- 6. out stores after the flag — drain overlaps next spin ----
        float4 o4 = { hp[0], hp[1], hp[2], hp[3] };
        *reinterpret_cast<float4*>(out + (size_t)rowg * 1024 + jq) = o4;
        if (t == 511) {
            *reinterpret_cast<float4*>(out + 16777216 + b * 1024 + jq) = o4;
            *reinterpret_cast<float4*>(out + 16809984 + b * 1024 + jq) = o4;
        }

        // ---- 7. gi/pad prefetch for t+1, LAST (off the ACK path) ----
        if (t < 511) {
            const short* gp = gi + (size_t)((t + 1) * 32 + b) * 3072 + jq;
            gr_.u = *reinterpret_cast<const unsigned long long*>(gp);
            gz_.u = *reinterpret_cast<const unsigned long long*>(gp + 1024);
            gn_.u = *reinterpret_cast<const unsigned long long*>(gp + 2048);
            pv = pad[(t + 1) * 32 + b];
        }
    }
}

// ---------------------------------------------------------------------------
extern "C" void kernel_launch(void* const* d_in, const int* in_sizes, int n_in,
                              void* d_out, int out_size, void* d_ws, size_t ws_size,
                              hipStream_t stream) {
    const float* X   = (const float*)d_in[0];
    const float* pad = (const float*)d_in[1];
    const float* Wih = (const float*)d_in[2];
    const float* Whh = (const float*)d_in[3];
    const float* bih = (const float*)d_in[4];
    const float* bhh = (const float*)d_in[5];
    float* out = (float*)d_out;

    char* ws = (char*)d_ws;
    short*    gi    = (short*)(ws);                      // 100,663,296 B
    short*    Wih_t = (short*)(ws + 100663296);          //   6,291,456 B (dead after gemm)
    short*    Whh_t = (short*)(ws + 106954752);          //   6,291,456 B
    unsigned long long* hb4 =
        (unsigned long long*)(ws + 100663296);           // reuses Wih_t: 131,072 B
    unsigned* flags = (unsigned*)(ws + 100663296 + 131072);  // 512 B

    hipLaunchKernelGGL(k_transpose_bf16, dim3(1536), dim3(256), 0, stream, Wih, Wih_t);
    hipLaunchKernelGGL(k_transpose_bf16, dim3(1536), dim3(256), 0, stream, Whh, Whh_t);
    hipLaunchKernelGGL(k_gemm_gi, dim3(128 * 24), dim3(256), 0, stream, X, Wih_t, gi);

    // Zero the h buffer (h0 = 0) + flags. Enqueued AFTER the gemm so the
    // Wih_t aliasing is stream-safe.
    hipMemsetAsync(hb4, 0, 131072 + 512, stream);

    hipFuncSetAttribute((const void*)k_gru,
                        hipFuncAttributeMaxDynamicSharedMemorySize, 99072);
    hipLaunchKernelGGL(k_gru, dim3(NB), dim3(128), 99072, stream,
                       pad, gi, Whh_t, bih, bhh, hb4, flags, out);
}